// Round 1
// baseline (185.078 us; speedup 1.0000x reference)
//
#include <hip/hip_runtime.h>

#define BATCH 32768
#define DIM   256
#define NEXP  8
#define MT    64          // rows per tile
#define STRIDE 264        // DIM + 8 bf16 pad (keeps 16B alignment)

typedef __bf16 bf16x8 __attribute__((ext_vector_type(8)));
typedef __bf16 bf16x4 __attribute__((ext_vector_type(4)));
typedef float  f32x16 __attribute__((ext_vector_type(16)));

static __device__ __forceinline__ float sigmoid_f(float x) {
    return __builtin_amdgcn_rcpf(1.f + __expf(-x));
}
static __device__ __forceinline__ float tanh_f(float x) {
    // 1 - 2/(e^{2x}+1): monotone-safe at +/-inf (no inf/inf)
    return 1.f - 2.f * __builtin_amdgcn_rcpf(__expf(2.f * x) + 1.f);
}
static __device__ __forceinline__ unsigned short f2b(float x) {
    union { __bf16 b; unsigned short u; } v; v.b = (__bf16)x; return v.u;
}

// ---- weight fp32 -> bf16 (one pass, grid 512x256 covers 131072 float4 per tensor)
__global__ void cvt_kernel(const float4* __restrict__ W1, const float4* __restrict__ W2,
                           ushort4* __restrict__ W1b, ushort4* __restrict__ W2b) {
    const int i = blockIdx.x * 256 + threadIdx.x;
    float4 a = W1[i];
    float4 b = W2[i];
    W1b[i] = make_ushort4(f2b(a.x), f2b(a.y), f2b(a.z), f2b(a.w));
    W2b[i] = make_ushort4(f2b(b.x), f2b(b.y), f2b(b.z), f2b(b.w));
}

// ---- per-expert counts (8 global atomics per block)
__global__ void count_kernel(const float* __restrict__ t, int* __restrict__ cnt) {
    __shared__ int h[NEXP];
    if (threadIdx.x < NEXP) h[threadIdx.x] = 0;
    __syncthreads();
    const int i = blockIdx.x * 256 + threadIdx.x;
    const int e = min((int)(t[i] * 8.0f), NEXP - 1);
    atomicAdd(&h[e], 1);
    __syncthreads();
    if (threadIdx.x < NEXP) atomicAdd(&cnt[threadIdx.x], h[threadIdx.x]);
}

// ---- scatter sample indices into contiguous per-expert regions
__global__ void scatter_kernel(const float* __restrict__ t, const int* __restrict__ cnt,
                               int* __restrict__ cursor, int* __restrict__ idxb) {
    __shared__ int h[NEXP], base[NEXP];
    if (threadIdx.x < NEXP) h[threadIdx.x] = 0;
    __syncthreads();
    const int i = blockIdx.x * 256 + threadIdx.x;
    const int e = min((int)(t[i] * 8.0f), NEXP - 1);
    const int lr = atomicAdd(&h[e], 1);
    __syncthreads();
    if (threadIdx.x < NEXP) {
        int pre = 0;
        for (int j = 0; j < threadIdx.x; ++j) pre += cnt[j];
        base[threadIdx.x] = pre + atomicAdd(&cursor[threadIdx.x], h[threadIdx.x]);
    }
    __syncthreads();
    idxb[base[e] + lr] = i;
}

// ---- grouped fused 2-layer MLP, persistent blocks
__global__ void mlp_kernel(const float* __restrict__ y,
                           const float* __restrict__ scales,
                           const float* __restrict__ shifta,
                           const float* __restrict__ shiftb,
                           const float* __restrict__ b1,
                           const float* __restrict__ b2,
                           const unsigned short* __restrict__ W1b,
                           const unsigned short* __restrict__ W2b,
                           const int* __restrict__ cnt,
                           const int* __restrict__ idxb,
                           float* __restrict__ out) {
    __shared__ __bf16 ab[MT * STRIDE];   // y tile (bf16), then overwritten with tanh(h)
    __shared__ int rows[MT];

    const int tx   = threadIdx.x;
    const int wave = tx >> 6;
    const int lane = tx & 63;
    const int nl   = lane & 31;   // MFMA m/n lane index
    const int kh   = lane >> 5;   // k half (0: k 0-7, 1: k 8-15)
    const int wm   = wave & 1;    // row half of tile (32 rows)
    const int wn   = wave >> 1;   // col half (128 cols)

    int c[NEXP], tp[NEXP + 1], rp[NEXP + 1];
    tp[0] = 0; rp[0] = 0;
#pragma unroll
    for (int e = 0; e < NEXP; ++e) {
        c[e] = cnt[e];
        tp[e + 1] = tp[e] + ((c[e] + MT - 1) >> 6);
        rp[e + 1] = rp[e] + c[e];
    }
    const int total = tp[NEXP];

    const float sa = sigmoid_f(shifta[0]);
    const float sb = sigmoid_f(shiftb[0]);
    const float av = -sa;               // EIGINIT + sa*(EIGMIN-EIGINIT)
    const float bvv = sb;               // EIGINIT + sb*(EIGMAX-EIGINIT)
    const float k1 = 0.5f * (bvv - av);
    const float k2 = 0.5f * (av + bvv);

    for (int tile = blockIdx.x; tile < total; tile += gridDim.x) {
        int e = 0;
#pragma unroll
        for (int j = 0; j < NEXP; ++j) if (tile >= tp[j + 1]) e = j + 1;
        const int tt    = tile - tp[e];
        const int rbase = tt * MT;
        const int nrows = min(MT, c[e] - rbase);
        const int* idx_e = idxb + rp[e];

        __syncthreads();   // previous iteration's readers of ab/rows are done
        // stage gathered y rows -> bf16 LDS tile; one row per wave per pass
#pragma unroll
        for (int pass = 0; pass < 16; ++pass) {
            const int r  = pass * 4 + wave;
            const int rr = (r < nrows) ? r : 0;
            const int g  = idx_e[rbase + rr];
            if (lane == 0) rows[r] = (r < nrows) ? g : -1;
            const float4 v = *(const float4*)(y + (long)g * DIM + lane * 4);
            bf16x4 w;
            w[0] = (__bf16)v.x; w[1] = (__bf16)v.y; w[2] = (__bf16)v.z; w[3] = (__bf16)v.w;
            *(bf16x4*)(ab + r * STRIDE + lane * 4) = w;
        }
        __syncthreads();

        const __bf16* apt = ab + (wm * 32 + nl) * STRIDE + kh * 8;

        // ---- GEMM1: h = y @ W1[e]^T  (A from LDS, B direct from global bf16)
        const unsigned short* wrow1 = W1b + (((e << 8) | (wn * 128 + nl)) << 8) + (kh << 3);
        f32x16 acc[4] = {};
#pragma unroll
        for (int ks = 0; ks < 16; ++ks) {
            bf16x8 a = *(const bf16x8*)(apt + ks * 16);
#pragma unroll
            for (int ni = 0; ni < 4; ++ni) {
                bf16x8 b = *(const bf16x8*)(wrow1 + ni * (32 * 256) + ks * 16);
                acc[ni] = __builtin_amdgcn_mfma_f32_32x32x16_bf16(a, b, acc[ni], 0, 0, 0);
            }
        }
        __syncthreads();   // all GEMM1 reads of ab complete

        // ---- tanh(h + b1) -> ab (C/D layout: col=lane&31, row=(r&3)+8*(r>>2)+4*kh)
#pragma unroll
        for (int ni = 0; ni < 4; ++ni) {
            const int n = wn * 128 + ni * 32 + nl;
            const float b1v = b1[(e << 8) | n];
#pragma unroll
            for (int r = 0; r < 16; ++r) {
                const int row = (r & 3) + ((r >> 2) << 3) + (kh << 2);
                ab[(wm * 32 + row) * STRIDE + n] = (__bf16)tanh_f(acc[ni][r] + b1v);
            }
        }
        __syncthreads();

        // ---- GEMM2: f = h @ W2[e]^T
        const unsigned short* wrow2 = W2b + (((e << 8) | (wn * 128 + nl)) << 8) + (kh << 3);
        f32x16 acc2[4] = {};
#pragma unroll
        for (int ks = 0; ks < 16; ++ks) {
            bf16x8 a = *(const bf16x8*)(apt + ks * 16);
#pragma unroll
            for (int ni = 0; ni < 4; ++ni) {
                bf16x8 b = *(const bf16x8*)(wrow2 + ni * (32 * 256) + ks * 16);
                acc2[ni] = __builtin_amdgcn_mfma_f32_32x32x16_bf16(a, b, acc2[ni], 0, 0, 0);
            }
        }

        // ---- epilogue: out = k1*sig(scales)*(f+b2) + k2*y, scattered store
#pragma unroll
        for (int ni = 0; ni < 4; ++ni) {
            const int n = wn * 128 + ni * 32 + nl;
            const float c1  = k1 * sigmoid_f(scales[n]);
            const float b2v = b2[(e << 8) | n];
#pragma unroll
            for (int r = 0; r < 16; ++r) {
                const int row = wm * 32 + (r & 3) + ((r >> 2) << 3) + (kh << 2);
                const int g = rows[row];
                if (g >= 0) {
                    const float yv = y[(long)g * DIM + n];
                    out[(long)g * DIM + n] = c1 * (acc2[ni][r] + b2v) + k2 * yv;
                }
            }
        }
    }
}

extern "C" void kernel_launch(void* const* d_in, const int* in_sizes, int n_in,
                              void* d_out, int out_size, void* d_ws, size_t ws_size,
                              hipStream_t stream) {
    const float* t      = (const float*)d_in[0];
    const float* y      = (const float*)d_in[1];
    const float* W1     = (const float*)d_in[2];
    const float* b1     = (const float*)d_in[3];
    const float* W2     = (const float*)d_in[4];
    const float* b2     = (const float*)d_in[5];
    const float* scales = (const float*)d_in[6];
    const float* shifta = (const float*)d_in[7];
    const float* shiftb = (const float*)d_in[8];
    float* out = (float*)d_out;

    char* ws = (char*)d_ws;
    int* cnt    = (int*)ws;                 // [8]
    int* cursor = (int*)(ws + 32);          // [8]
    int* idxb   = (int*)(ws + 256);         // [32768]
    unsigned short* W1b = (unsigned short*)(ws + 256 + BATCH * 4);          // 8*256*256 bf16
    unsigned short* W2b = W1b + NEXP * DIM * DIM;

    hipMemsetAsync(ws, 0, 64, stream);
    cvt_kernel<<<512, 256, 0, stream>>>((const float4*)W1, (const float4*)W2,
                                        (ushort4*)W1b, (ushort4*)W2b);
    count_kernel<<<BATCH / 256, 256, 0, stream>>>(t, cnt);
    scatter_kernel<<<BATCH / 256, 256, 0, stream>>>(t, cnt, cursor, idxb);
    mlp_kernel<<<520, 256, 0, stream>>>(y, scales, shifta, shiftb, b1, b2,
                                        W1b, W2b, cnt, idxb, out);
}

// Round 2
// 156.664 us; speedup vs baseline: 1.1814x; 1.1814x over previous
//
#include <hip/hip_runtime.h>

#define BATCH 32768
#define DIM   256
#define NEXP  8
#define MT    32          // rows per tile
#define STRIDE 264        // DIM + 8 bf16 pad (16B-aligned rows; measured 0 bank conflicts)

typedef __bf16 bf16x8 __attribute__((ext_vector_type(8)));
typedef __bf16 bf16x4 __attribute__((ext_vector_type(4)));
typedef float  f32x16 __attribute__((ext_vector_type(16)));

static __device__ __forceinline__ float sigmoid_f(float x) {
    return __builtin_amdgcn_rcpf(1.f + __expf(-x));
}
static __device__ __forceinline__ float tanh_f(float x) {
    // 1 - 2/(e^{2x}+1): monotone-safe at +/-inf
    return 1.f - 2.f * __builtin_amdgcn_rcpf(__expf(2.f * x) + 1.f);
}
static __device__ __forceinline__ unsigned short f2b(float x) {
    union { __bf16 b; unsigned short u; } v; v.b = (__bf16)x; return v.u;
}

// ---- fused prep: blocks 0..511 convert W1/W2 fp32->bf16; blocks 512..639
// scatter sample indices into fixed per-expert regions idxb[e*BATCH + ...]
__global__ void prep_kernel(const float4* __restrict__ W1, const float4* __restrict__ W2,
                            const float* __restrict__ t,
                            ushort4* __restrict__ W1b, ushort4* __restrict__ W2b,
                            int* __restrict__ cursor, int* __restrict__ idxb) {
    const int b = blockIdx.x;
    if (b < 512) {
        const int i = b * 256 + threadIdx.x;
        const float4 a = W1[i];
        const float4 c = W2[i];
        W1b[i] = make_ushort4(f2b(a.x), f2b(a.y), f2b(a.z), f2b(a.w));
        W2b[i] = make_ushort4(f2b(c.x), f2b(c.y), f2b(c.z), f2b(c.w));
    } else {
        __shared__ int h[NEXP], base[NEXP];
        if (threadIdx.x < NEXP) h[threadIdx.x] = 0;
        __syncthreads();
        const int i = (b - 512) * 256 + threadIdx.x;
        const int e = min((int)(t[i] * 8.0f), NEXP - 1);
        const int lr = atomicAdd(&h[e], 1);          // LDS-local rank
        __syncthreads();
        if (threadIdx.x < NEXP)
            base[threadIdx.x] = atomicAdd(&cursor[threadIdx.x], h[threadIdx.x]);
        __syncthreads();
        idxb[e * BATCH + base[e] + lr] = i;
    }
}

// ---- grouped fused 2-layer MLP. MT=32 rows/tile -> ~1032 tiles -> 4 blocks/CU.
// Each wave: 32 rows x 64 cols (2x mfma_32x32x16 acc tiles).
__global__ void __launch_bounds__(256, 4)
mlp_kernel(const float* __restrict__ y,
           const float* __restrict__ scales,
           const float* __restrict__ shifta,
           const float* __restrict__ shiftb,
           const float* __restrict__ b1,
           const float* __restrict__ b2,
           const unsigned short* __restrict__ W1b,
           const unsigned short* __restrict__ W2b,
           const int* __restrict__ cnt,
           const int* __restrict__ idxb,
           float* __restrict__ out) {
    __shared__ __bf16 ab[MT * STRIDE];   // y tile (bf16), then tanh(h)
    __shared__ int rows[MT];

    const int tx   = threadIdx.x;
    const int wave = tx >> 6;
    const int lane = tx & 63;
    const int nl   = lane & 31;   // MFMA m/n lane index
    const int kh   = lane >> 5;   // k half
    const int nbase = wave * 64;  // this wave's output-column base

    int c[NEXP], tp[NEXP + 1];
    tp[0] = 0;
#pragma unroll
    for (int e = 0; e < NEXP; ++e) {
        c[e] = cnt[e];
        tp[e + 1] = tp[e] + ((c[e] + MT - 1) >> 5);
    }
    const int total = tp[NEXP];

    const float sa = sigmoid_f(shifta[0]);
    const float sb = sigmoid_f(shiftb[0]);
    const float av = -sa;               // EIGINIT + sa*(EIGMIN-EIGINIT)
    const float bvv = sb;               // EIGINIT + sb*(EIGMAX-EIGINIT)
    const float k1 = 0.5f * (bvv - av);
    const float k2 = 0.5f * (av + bvv);
    const bool needy = (k2 != 0.0f);    // with given inputs k2==0 exactly

    for (int tile = blockIdx.x; tile < total; tile += gridDim.x) {
        int e = 0;
#pragma unroll
        for (int j = 0; j < NEXP; ++j) if (tile >= tp[j + 1]) e = j + 1;
        const int rbase = (tile - tp[e]) * MT;
        const int nrows = min(MT, c[e] - rbase);
        const int* idx_e = idxb + e * BATCH;

        __syncthreads();   // previous iteration's readers of ab/rows done
        // stage gathered y rows -> bf16 LDS tile; one row per wave per pass
#pragma unroll
        for (int pass = 0; pass < 8; ++pass) {
            const int r  = pass * 4 + wave;
            const int rr = (r < nrows) ? r : 0;
            const int g  = idx_e[rbase + rr];
            if (lane == 0) rows[r] = (r < nrows) ? g : -1;
            const float4 v = *(const float4*)(y + (long)g * DIM + lane * 4);
            bf16x4 w;
            w[0] = (__bf16)v.x; w[1] = (__bf16)v.y; w[2] = (__bf16)v.z; w[3] = (__bf16)v.w;
            *(bf16x4*)(ab + r * STRIDE + lane * 4) = w;
        }
        __syncthreads();

        const __bf16* apt = ab + nl * STRIDE + kh * 8;

        // ---- GEMM1: h = y @ W1[e]^T  (A from LDS, B direct from global bf16)
        const unsigned short* w1p = W1b + (((e << 8) | (nbase + nl)) << 8) + (kh << 3);
        f32x16 acc[2] = {};
#pragma unroll
        for (int ks = 0; ks < 16; ++ks) {
            bf16x8 a = *(const bf16x8*)(apt + ks * 16);
#pragma unroll
            for (int ni = 0; ni < 2; ++ni) {
                bf16x8 bb = *(const bf16x8*)(w1p + ni * (32 * 256) + ks * 16);
                acc[ni] = __builtin_amdgcn_mfma_f32_32x32x16_bf16(a, bb, acc[ni], 0, 0, 0);
            }
        }
        __syncthreads();   // all GEMM1 reads of ab complete

        // ---- tanh(h + b1) -> ab (C/D layout: col=lane&31, row=(r&3)+8*(r>>2)+4*kh)
#pragma unroll
        for (int ni = 0; ni < 2; ++ni) {
            const int n = nbase + ni * 32 + nl;
            const float b1v = b1[(e << 8) | n];
#pragma unroll
            for (int r = 0; r < 16; ++r) {
                const int row = (r & 3) + ((r >> 2) << 3) + (kh << 2);
                ab[row * STRIDE + n] = (__bf16)tanh_f(acc[ni][r] + b1v);
            }
        }
        __syncthreads();

        // ---- GEMM2: f = h @ W2[e]^T
        const unsigned short* w2p = W2b + (((e << 8) | (nbase + nl)) << 8) + (kh << 3);
        f32x16 acc2[2] = {};
#pragma unroll
        for (int ks = 0; ks < 16; ++ks) {
            bf16x8 a = *(const bf16x8*)(apt + ks * 16);
#pragma unroll
            for (int ni = 0; ni < 2; ++ni) {
                bf16x8 bb = *(const bf16x8*)(w2p + ni * (32 * 256) + ks * 16);
                acc2[ni] = __builtin_amdgcn_mfma_f32_32x32x16_bf16(a, bb, acc2[ni], 0, 0, 0);
            }
        }

        // ---- epilogue: out = k1*sig(scales)*(f+b2) + k2*y, scattered store
#pragma unroll
        for (int ni = 0; ni < 2; ++ni) {
            const int n = nbase + ni * 32 + nl;
            const float c1  = k1 * sigmoid_f(scales[n]);
            const float b2v = b2[(e << 8) | n];
#pragma unroll
            for (int r = 0; r < 16; ++r) {
                const int row = (r & 3) + ((r >> 2) << 3) + (kh << 2);
                const int g = rows[row];
                if (g >= 0) {
                    float res = c1 * (acc2[ni][r] + b2v);
                    if (needy) res += k2 * y[(long)g * DIM + n];
                    out[(long)g * DIM + n] = res;
                }
            }
        }
    }
}

extern "C" void kernel_launch(void* const* d_in, const int* in_sizes, int n_in,
                              void* d_out, int out_size, void* d_ws, size_t ws_size,
                              hipStream_t stream) {
    const float* t      = (const float*)d_in[0];
    const float* y      = (const float*)d_in[1];
    const float* W1     = (const float*)d_in[2];
    const float* b1     = (const float*)d_in[3];
    const float* W2     = (const float*)d_in[4];
    const float* b2     = (const float*)d_in[5];
    const float* scales = (const float*)d_in[6];
    const float* shifta = (const float*)d_in[7];
    const float* shiftb = (const float*)d_in[8];
    float* out = (float*)d_out;

    char* ws = (char*)d_ws;
    int* cursor = (int*)ws;                               // [8]
    int* idxb   = (int*)(ws + 256);                       // [8][32768] fixed regions
    unsigned short* W1b = (unsigned short*)(ws + 256 + NEXP * BATCH * 4);
    unsigned short* W2b = W1b + NEXP * DIM * DIM;

    hipMemsetAsync(cursor, 0, 32, stream);
    prep_kernel<<<640, 256, 0, stream>>>((const float4*)W1, (const float4*)W2, t,
                                         (ushort4*)W1b, (ushort4*)W2b, cursor, idxb);
    mlp_kernel<<<1032, 256, 0, stream>>>(y, scales, shifta, shiftb, b1, b2,
                                         W1b, W2b, cursor, idxb, out);
}